// Round 1
// baseline (1517.094 us; speedup 1.0000x reference)
//
#include <hip/hip_runtime.h>
#include <cmath>

namespace {
constexpr int Bn = 128, Tn = 128, BTn = Bn * Tn;
constexpr int CONTn = 16, HIDn = 128, EMBn = 64;
constexpr int Kn = 8192, CEn = 6, VSPn = 2000, VLCn = 32, FINn = 3 * HIDn;

// ---- workspace layout (float units) ----
constexpr size_t WS_NAIP2 = 0;                               // B*HID
constexpr size_t WS_ZE    = WS_NAIP2 + (size_t)Bn * HIDn;    // BT*EMB
constexpr size_t WS_ZQ    = WS_ZE + (size_t)BTn * EMBn;      // BT*EMB
constexpr size_t WS_H     = WS_ZQ + (size_t)BTn * EMBn;      // BT*HID
constexpr size_t WS_ESQ   = WS_H + (size_t)BTn * HIDn;       // K
constexpr size_t WS_PART  = WS_ESQ + Kn;                     // 256 partial loss sums
constexpr size_t WS_CNT   = WS_PART + 256;                   // K ints

// ---- output layout (float units) ----
constexpr size_t O_CONT = 0;
constexpr size_t O_SP   = O_CONT + (size_t)BTn * CONTn;
constexpr size_t O_LC   = O_SP + (size_t)BTn * VSPn;
constexpr size_t O_CAN  = O_LC + (size_t)BTn * VLCn;
constexpr size_t O_IDX  = O_CAN + Bn;
constexpr size_t O_LOSS = O_IDX + BTn;
constexpr size_t O_PPL  = O_LOSS + 1;
} // namespace

__device__ __forceinline__ float nan0(float v) {
    return __builtin_isfinite(v) ? v : 0.0f;
}
__device__ __forceinline__ float dot4(float4 a, float4 b) {
    return a.x * b.x + a.y * b.y + a.z * b.z + a.w * b.w;
}

// ---------------------------------------------------------------- K0: zero counts + codebook row norms
__global__ __launch_bounds__(256) void k_esq_zero(const float* __restrict__ cb,
                                                  float* __restrict__ e_sq,
                                                  int* __restrict__ counts) {
    int i = blockIdx.x * 256 + threadIdx.x;
    if (i < Kn) {
        counts[i] = 0;
        const float4* r = (const float4*)(cb + (size_t)i * EMBn);
        float s = 0.f;
#pragma unroll
        for (int j = 0; j < 16; ++j) { float4 v = r[j]; s += dot4(v, v); }
        e_sq[i] = s;
    }
}

// ---------------------------------------------------------------- K1: naip conv + proj -> naip2 (B x HID)
__global__ __launch_bounds__(128) void k_naip(const float* __restrict__ naip,
                                              const float* __restrict__ conv_w,
                                              const float* __restrict__ conv_b,
                                              const float* __restrict__ pw,
                                              const float* __restrict__ pb,
                                              float* __restrict__ naip2) {
    int b = blockIdx.x, o = threadIdx.x;
    __shared__ float feat[HIDn];
    float acc = conv_b[o];
#pragma unroll
    for (int i = 0; i < 9; ++i) acc += nan0(naip[b * 9 + i]) * conv_w[o * 9 + i];
    feat[o] = fmaxf(acc, 0.f);
    __syncthreads();
    float a2 = pb[o];
    const float4* wr = (const float4*)(pw + (size_t)o * HIDn);
    const float4* fr = (const float4*)feat;
#pragma unroll
    for (int j = 0; j < 32; ++j) a2 += dot4(fr[j], wr[j]);
    naip2[(size_t)b * HIDn + o] = a2;
}

// ---------------------------------------------------------------- K2: fused inputs -> z_e (BT x EMB)
__global__ __launch_bounds__(256) void k_ze(
    const float* __restrict__ cont, const int* __restrict__ cat,
    const float* __restrict__ emb_sp, const float* __restrict__ emb_lc,
    const float* __restrict__ cpw, const float* __restrict__ cpb,
    const float* __restrict__ caw, const float* __restrict__ cab,
    const float* __restrict__ f1w, const float* __restrict__ f1b,
    const float* __restrict__ f2w, const float* __restrict__ f2b,
    const float* __restrict__ naip2, float* __restrict__ z_e) {
    const int tok0 = blockIdx.x * 16;
    const int tid = threadIdx.x;
    __shared__ float fused[16][FINn + 4]; // stride 388 floats (1552 B, 16B aligned)
    __shared__ float h1[16][HIDn + 4];    // stride 132

    // A1: naip broadcast part
    for (int idx = tid; idx < 16 * HIDn; idx += 256) {
        int t = idx >> 7, j = idx & 127;
        int b = (tok0 + t) / Tn;
        fused[t][j] = naip2[(size_t)b * HIDn + j];
    }
    // A2: cont projection
    for (int idx = tid; idx < 16 * HIDn; idx += 256) {
        int t = idx >> 7, o = idx & 127;
        int tok = tok0 + t;
        const float4* cp = (const float4*)(cont + (size_t)tok * CONTn);
        const float4* wr = (const float4*)(cpw + (size_t)o * CONTn);
        float a = cpb[o];
#pragma unroll
        for (int q = 0; q < 4; ++q) {
            float4 c4 = cp[q], w4 = wr[q];
            a += nan0(c4.x) * w4.x + nan0(c4.y) * w4.y + nan0(c4.z) * w4.z + nan0(c4.w) * w4.w;
        }
        fused[t][HIDn + o] = a;
    }
    // A3: cat embedding projection
    for (int idx = tid; idx < 16 * HIDn; idx += 256) {
        int t = idx >> 7, o = idx & 127;
        int tok = tok0 + t;
        int c0 = cat[tok * 2], c1 = cat[tok * 2 + 1];
        const float* e0 = emb_sp + (size_t)c0 * CEn;
        const float* e1 = emb_lc + (size_t)c1 * CEn;
        const float* wr = caw + (size_t)o * (2 * CEn);
        float a = cab[o];
#pragma unroll
        for (int i = 0; i < CEn; ++i) a += e0[i] * wr[i];
#pragma unroll
        for (int i = 0; i < CEn; ++i) a += e1[i] * wr[CEn + i];
        fused[t][2 * HIDn + o] = a;
    }
    __syncthreads();
    // B: h1 = relu(fused @ f1w^T + b)
    {
        int o = tid >> 1, half = tid & 1;
        float acc[8];
        float bv = f1b[o];
#pragma unroll
        for (int t = 0; t < 8; ++t) acc[t] = bv;
        const float4* wr = (const float4*)(f1w + (size_t)o * FINn);
        for (int kk = 0; kk < FINn / 4; ++kk) {
            float4 w = wr[kk];
#pragma unroll
            for (int t = 0; t < 8; ++t) {
                float4 f = ((const float4*)&fused[half * 8 + t][0])[kk];
                acc[t] += dot4(f, w);
            }
        }
#pragma unroll
        for (int t = 0; t < 8; ++t) h1[half * 8 + t][o] = fmaxf(acc[t], 0.f);
    }
    __syncthreads();
    // C: z_e = h1 @ f2w^T + b
    {
        int o = tid & 63, tg = tid >> 6;
        float acc[4];
        float bv = f2b[o];
#pragma unroll
        for (int t = 0; t < 4; ++t) acc[t] = bv;
        const float4* wr = (const float4*)(f2w + (size_t)o * HIDn);
        for (int kk = 0; kk < HIDn / 4; ++kk) {
            float4 w = wr[kk];
#pragma unroll
            for (int t = 0; t < 4; ++t) {
                float4 f = ((const float4*)&h1[tg * 4 + t][0])[kk];
                acc[t] += dot4(f, w);
            }
        }
#pragma unroll
        for (int t = 0; t < 4; ++t) z_e[(size_t)(tok0 + tg * 4 + t) * EMBn + o] = acc[t];
    }
}

// ---------------------------------------------------------------- K3: VQ argmin + z_q gather + loss partial + counts
// block: 128 threads (x=tid&15 code groups, y=tid>>4 token groups); 64 toks x (tiles of 128 codes)
__global__ __launch_bounds__(128) void k_vq(
    const float* __restrict__ z_e, const float* __restrict__ cb,
    const float* __restrict__ e_sq, float* __restrict__ z_q,
    float* __restrict__ idx_out, int* __restrict__ counts,
    float* __restrict__ partials) {
    const int tid = threadIdx.x;
    const int x = tid & 15;  // 16 code columns, 8 codes each (stride 16)
    const int y = tid >> 4;  // 8 token rows, 8 toks each
    const int tok0 = blockIdx.x * 64;

    __shared__ float zt[64][68];
    __shared__ float ct[128][68];
    __shared__ float es[128];
    __shared__ float rd[64][16];
    __shared__ int ri[64][16];
    __shared__ int bidx[64];
    __shared__ float wsum[2];

    for (int idx = tid; idx < 64 * 16; idx += 128) {
        int t = idx >> 4, q = idx & 15;
        ((float4*)&zt[t][0])[q] = ((const float4*)(z_e + (size_t)(tok0 + t) * EMBn))[q];
    }

    float bd[8];
    int bi[8];
#pragma unroll
    for (int t = 0; t < 8; ++t) { bd[t] = INFINITY; bi[t] = 0; }

    for (int c0 = 0; c0 < Kn; c0 += 128) {
        __syncthreads();
        for (int idx = tid; idx < 128 * 16; idx += 128) {
            int c = idx >> 4, q = idx & 15;
            ((float4*)&ct[c][0])[q] = ((const float4*)(cb + (size_t)(c0 + c) * EMBn))[q];
        }
        es[tid] = e_sq[c0 + tid]; // 128 threads, 128 entries
        __syncthreads();

        float acc[8][8];
#pragma unroll
        for (int t = 0; t < 8; ++t)
#pragma unroll
            for (int j = 0; j < 8; ++j) acc[t][j] = 0.f;

#pragma unroll
        for (int kk = 0; kk < 16; ++kk) {
            float4 zz[8];
#pragma unroll
            for (int t = 0; t < 8; ++t) zz[t] = ((const float4*)&zt[y * 8 + t][0])[kk];
#pragma unroll
            for (int j = 0; j < 8; ++j) {
                float4 c4 = ((const float4*)&ct[x + 16 * j][0])[kk];
#pragma unroll
                for (int t = 0; t < 8; ++t) acc[t][j] += dot4(zz[t], c4);
            }
        }
#pragma unroll
        for (int j = 0; j < 8; ++j) {
            int c = c0 + x + 16 * j;
            float e = es[x + 16 * j];
#pragma unroll
            for (int t = 0; t < 8; ++t) {
                float d = e - 2.f * acc[t][j];
                if (d < bd[t]) { bd[t] = d; bi[t] = c; } // codes visited ascending per thread
            }
        }
    }
#pragma unroll
    for (int t = 0; t < 8; ++t) { rd[y * 8 + t][x] = bd[t]; ri[y * 8 + t][x] = bi[t]; }
    __syncthreads();
    if (tid < 64) {
        float best = rd[tid][0];
        int b_ = ri[tid][0];
#pragma unroll
        for (int xx = 1; xx < 16; ++xx) {
            float d = rd[tid][xx];
            int i2 = ri[tid][xx];
            if (d < best || (d == best && i2 < b_)) { best = d; b_ = i2; } // lowest-index tie-break
        }
        bidx[tid] = b_;
        idx_out[tok0 + tid] = (float)b_;
        atomicAdd(&counts[b_], 1);
    }
    __syncthreads();
    // z_q gather + loss partial
    float lsum = 0.f;
    for (int idx = tid; idx < 64 * 16; idx += 128) {
        int t = idx >> 4, q = idx & 15;
        float4 cq = ((const float4*)(cb + (size_t)bidx[t] * EMBn))[q];
        ((float4*)(z_q + (size_t)(tok0 + t) * EMBn))[q] = cq;
        float4 zz = ((const float4*)&zt[t][0])[q];
        float dx = zz.x - cq.x, dy = zz.y - cq.y, dz = zz.z - cq.z, dw = zz.w - cq.w;
        lsum += dx * dx + dy * dy + dz * dz + dw * dw;
    }
#pragma unroll
    for (int off = 32; off > 0; off >>= 1) lsum += __shfl_down(lsum, off, 64);
    if ((tid & 63) == 0) wsum[tid >> 6] = lsum;
    __syncthreads();
    if (tid == 0) partials[blockIdx.x] = wsum[0] + wsum[1];
}

// ---------------------------------------------------------------- K4: backbone + small heads
__global__ __launch_bounds__(256) void k_backbone(
    const float* __restrict__ z_q,
    const float* __restrict__ bb1w, const float* __restrict__ bb1b,
    const float* __restrict__ bb2w, const float* __restrict__ bb2b,
    const float* __restrict__ chw, const float* __restrict__ chb,
    const float* __restrict__ lcw, const float* __restrict__ lcb,
    float* __restrict__ h_out, float* __restrict__ cont_rec, float* __restrict__ lc_out) {
    const int tid = threadIdx.x;
    const int tok0 = blockIdx.x * 16;
    __shared__ float zq[16][68];
    __shared__ float h1[16][HIDn + 4];
    __shared__ float h2[16][HIDn + 4];
    {
        int t = tid >> 4, q = tid & 15;
        ((float4*)&zq[t][0])[q] = ((const float4*)(z_q + (size_t)(tok0 + t) * EMBn))[q];
    }
    __syncthreads();
    {
        int o = tid >> 1, half = tid & 1;
        float acc[8];
        float bv = bb1b[o];
#pragma unroll
        for (int t = 0; t < 8; ++t) acc[t] = bv;
        const float4* wr = (const float4*)(bb1w + (size_t)o * EMBn);
#pragma unroll
        for (int kk = 0; kk < 16; ++kk) {
            float4 w = wr[kk];
#pragma unroll
            for (int t = 0; t < 8; ++t) acc[t] += dot4(((const float4*)&zq[half * 8 + t][0])[kk], w);
        }
#pragma unroll
        for (int t = 0; t < 8; ++t) h1[half * 8 + t][o] = fmaxf(acc[t], 0.f);
    }
    __syncthreads();
    {
        int o = tid >> 1, half = tid & 1;
        float acc[8];
        float bv = bb2b[o];
#pragma unroll
        for (int t = 0; t < 8; ++t) acc[t] = bv;
        const float4* wr = (const float4*)(bb2w + (size_t)o * HIDn);
        for (int kk = 0; kk < 32; ++kk) {
            float4 w = wr[kk];
#pragma unroll
            for (int t = 0; t < 8; ++t) acc[t] += dot4(((const float4*)&h1[half * 8 + t][0])[kk], w);
        }
#pragma unroll
        for (int t = 0; t < 8; ++t) {
            float v = fmaxf(acc[t], 0.f);
            h2[half * 8 + t][o] = v;
            h_out[(size_t)(tok0 + half * 8 + t) * HIDn + o] = v;
        }
    }
    __syncthreads();
    {
        int t = tid >> 4, o = tid & 15;
        float a = chb[o];
        const float4* wr = (const float4*)(chw + (size_t)o * HIDn);
#pragma unroll
        for (int kk = 0; kk < 32; ++kk) a += dot4(((const float4*)&h2[t][0])[kk], wr[kk]);
        cont_rec[(size_t)(tok0 + t) * CONTn + o] = a;
    }
    for (int idx = tid; idx < 16 * 32; idx += 256) {
        int t = idx >> 5, o = idx & 31;
        float a = lcb[o];
        const float4* wr = (const float4*)(lcw + (size_t)o * HIDn);
#pragma unroll
        for (int kk = 0; kk < 32; ++kk) a += dot4(((const float4*)&h2[t][0])[kk], wr[kk]);
        lc_out[(size_t)(tok0 + t) * VLCn + o] = a;
    }
}

// ---------------------------------------------------------------- K5: sp_logits GEMM (16384x128)@(128->2000)
// block 256 threads (x=tid&15, y=tid>>4); tile 128 toks x 128 vocab; 8x8 per thread; K in quarters of 32
__global__ __launch_bounds__(256) void k_sp(const float* __restrict__ h,
                                            const float* __restrict__ w,
                                            const float* __restrict__ bias,
                                            float* __restrict__ out) {
    const int tid = threadIdx.x;
    const int x = tid & 15, y = tid >> 4;
    const int v0 = blockIdx.x * 128;
    const int tok0 = blockIdx.y * 128;
    __shared__ float ht[128][36];
    __shared__ float wt[128][36];
    float acc[8][8];
#pragma unroll
    for (int t = 0; t < 8; ++t)
#pragma unroll
        for (int j = 0; j < 8; ++j) acc[t][j] = 0.f;

    for (int kq = 0; kq < 4; ++kq) {
        __syncthreads();
        for (int idx = tid; idx < 128 * 8; idx += 256) {
            int t = idx >> 3, q = idx & 7;
            ((float4*)&ht[t][0])[q] = ((const float4*)(h + (size_t)(tok0 + t) * HIDn + kq * 32))[q];
        }
        for (int idx = tid; idx < 128 * 8; idx += 256) {
            int r = idx >> 3, q = idx & 7;
            int v = v0 + r;
            float4 val = make_float4(0.f, 0.f, 0.f, 0.f);
            if (v < VSPn) val = ((const float4*)(w + (size_t)v * HIDn + kq * 32))[q];
            ((float4*)&wt[r][0])[q] = val;
        }
        __syncthreads();
#pragma unroll
        for (int kk = 0; kk < 8; ++kk) {
            float4 hh[8];
#pragma unroll
            for (int t = 0; t < 8; ++t) hh[t] = ((const float4*)&ht[y * 8 + t][0])[kk];
#pragma unroll
            for (int j = 0; j < 8; ++j) {
                float4 ww = ((const float4*)&wt[x + 16 * j][0])[kk];
#pragma unroll
                for (int t = 0; t < 8; ++t) acc[t][j] += dot4(hh[t], ww);
            }
        }
    }
#pragma unroll
    for (int j = 0; j < 8; ++j) {
        int v = v0 + x + 16 * j;
        if (v < VSPn) {
            float bv = bias[v];
#pragma unroll
            for (int t = 0; t < 8; ++t)
                out[(size_t)(tok0 + y * 8 + t) * VSPn + v] = acc[t][j] + bv;
        }
    }
}

// ---------------------------------------------------------------- K6: canopy head on h[:, -1, :]
__global__ __launch_bounds__(128) void k_canopy(const float* __restrict__ h,
                                                const float* __restrict__ w1,
                                                const float* __restrict__ b1,
                                                const float* __restrict__ w2,
                                                const float* __restrict__ b2,
                                                float* __restrict__ can) {
    int b = blockIdx.x, o = threadIdx.x;
    __shared__ float r[128];
    const float4* hr = (const float4*)(h + (size_t)(b * Tn + Tn - 1) * HIDn);
    const float4* wr = (const float4*)(w1 + (size_t)o * HIDn);
    float a = b1[o];
#pragma unroll
    for (int kk = 0; kk < 32; ++kk) a += dot4(hr[kk], wr[kk]);
    r[o] = fmaxf(a, 0.f) * w2[o];
    __syncthreads();
    for (int s = 64; s > 0; s >>= 1) {
        if (o < s) r[o] += r[o + s];
        __syncthreads();
    }
    if (o == 0) can[b] = r[0] + b2[0];
}

// ---------------------------------------------------------------- K7: loss + perplexity
__global__ __launch_bounds__(256) void k_finalize(const float* __restrict__ partials,
                                                  const int* __restrict__ counts,
                                                  float* __restrict__ out_loss,
                                                  float* __restrict__ out_ppl) {
    const int tid = threadIdx.x;
    __shared__ float red[256];
    red[tid] = partials[tid]; // exactly 256 partials
    __syncthreads();
    for (int s = 128; s > 0; s >>= 1) {
        if (tid < s) red[tid] += red[tid + s];
        __syncthreads();
    }
    float total = red[0];
    __syncthreads();
    float e = 0.f;
    for (int i = tid; i < Kn; i += 256) {
        float p = (float)counts[i] * (1.0f / BTn);
        e += p * logf(p + 1e-12f);
    }
    red[tid] = e;
    __syncthreads();
    for (int s = 128; s > 0; s >>= 1) {
        if (tid < s) red[tid] += red[tid + s];
        __syncthreads();
    }
    if (tid == 0) {
        out_loss[0] = 1.25f * total / (float)((size_t)BTn * EMBn);
        out_ppl[0] = expf(-red[0]);
    }
}

// ----------------------------------------------------------------
extern "C" void kernel_launch(void* const* d_in, const int* in_sizes, int n_in,
                              void* d_out, int out_size, void* d_ws, size_t ws_size,
                              hipStream_t stream) {
    const float* cont = (const float*)d_in[0];
    const float* naip = (const float*)d_in[1];
    const int* cat = (const int*)d_in[2];
    const float* emb_sp = (const float*)d_in[3];
    const float* emb_lc = (const float*)d_in[4];
    const float* conv_w = (const float*)d_in[5];
    const float* conv_b = (const float*)d_in[6];
    const float* npw = (const float*)d_in[7];
    const float* npb = (const float*)d_in[8];
    const float* cpw = (const float*)d_in[9];
    const float* cpb = (const float*)d_in[10];
    const float* caw = (const float*)d_in[11];
    const float* cab = (const float*)d_in[12];
    const float* f1w = (const float*)d_in[13];
    const float* f1b = (const float*)d_in[14];
    const float* f2w = (const float*)d_in[15];
    const float* f2b = (const float*)d_in[16];
    const float* cb = (const float*)d_in[17];
    const float* bb1w = (const float*)d_in[18];
    const float* bb1b = (const float*)d_in[19];
    const float* bb2w = (const float*)d_in[20];
    const float* bb2b = (const float*)d_in[21];
    const float* chw = (const float*)d_in[22];
    const float* chb = (const float*)d_in[23];
    const float* spw = (const float*)d_in[24];
    const float* spb = (const float*)d_in[25];
    const float* lcw = (const float*)d_in[26];
    const float* lcb = (const float*)d_in[27];
    const float* c1w = (const float*)d_in[28];
    const float* c1b = (const float*)d_in[29];
    const float* c2w = (const float*)d_in[30];
    const float* c2b = (const float*)d_in[31];

    float* out = (float*)d_out;
    float* ws = (float*)d_ws;
    float* naip2 = ws + WS_NAIP2;
    float* z_e = ws + WS_ZE;
    float* z_q = ws + WS_ZQ;
    float* h = ws + WS_H;
    float* e_sq = ws + WS_ESQ;
    float* parts = ws + WS_PART;
    int* counts = (int*)(ws + WS_CNT);

    k_esq_zero<<<dim3(Kn / 256), dim3(256), 0, stream>>>(cb, e_sq, counts);
    k_naip<<<dim3(Bn), dim3(128), 0, stream>>>(naip, conv_w, conv_b, npw, npb, naip2);
    k_ze<<<dim3(BTn / 16), dim3(256), 0, stream>>>(cont, cat, emb_sp, emb_lc, cpw, cpb, caw, cab,
                                                   f1w, f1b, f2w, f2b, naip2, z_e);
    k_vq<<<dim3(BTn / 64), dim3(128), 0, stream>>>(z_e, cb, e_sq, z_q, out + O_IDX, counts, parts);
    k_backbone<<<dim3(BTn / 16), dim3(256), 0, stream>>>(z_q, bb1w, bb1b, bb2w, bb2b, chw, chb,
                                                         lcw, lcb, h, out + O_CONT, out + O_LC);
    k_sp<<<dim3(16, BTn / 128), dim3(256), 0, stream>>>(h, spw, spb, out + O_SP);
    k_canopy<<<dim3(Bn), dim3(128), 0, stream>>>(h, c1w, c1b, c2w, c2b, out + O_CAN);
    k_finalize<<<dim3(1), dim3(256), 0, stream>>>(parts, counts, out + O_LOSS, out + O_PPL);
}

// Round 2
// 774.601 us; speedup vs baseline: 1.9585x; 1.9585x over previous
//
#include <hip/hip_runtime.h>
#include <cmath>

namespace {
constexpr int Bn = 128, Tn = 128, BTn = Bn * Tn;
constexpr int CONTn = 16, HIDn = 128, EMBn = 64;
constexpr int Kn = 8192, CEn = 6, VSPn = 2000, VLCn = 32, FINn = 3 * HIDn;
constexpr int VQ_CHUNKS = 8;              // 1024 codes per chunk
constexpr int VQ_TOK = 128;               // tokens per block

// ---- workspace layout (float units) ----
constexpr size_t WS_NAIP2 = 0;                               // B*HID
constexpr size_t WS_ZE    = WS_NAIP2 + (size_t)Bn * HIDn;    // BT*EMB
constexpr size_t WS_ZQ    = WS_ZE + (size_t)BTn * EMBn;      // BT*EMB
constexpr size_t WS_H     = WS_ZQ + (size_t)BTn * EMBn;      // BT*HID
constexpr size_t WS_ESQ   = WS_H + (size_t)BTn * HIDn;       // K
constexpr size_t WS_PART  = WS_ESQ + Kn;                     // 64 partial loss sums
constexpr size_t WS_CNT   = WS_PART + 64;                    // K ints
constexpr size_t WS_PD    = WS_CNT + Kn;                     // VQ_CHUNKS*BT floats
constexpr size_t WS_PI    = WS_PD + (size_t)VQ_CHUNKS * BTn; // VQ_CHUNKS*BT ints

// ---- output layout (float units) ----
constexpr size_t O_CONT = 0;
constexpr size_t O_SP   = O_CONT + (size_t)BTn * CONTn;
constexpr size_t O_LC   = O_SP + (size_t)BTn * VSPn;
constexpr size_t O_CAN  = O_LC + (size_t)BTn * VLCn;
constexpr size_t O_IDX  = O_CAN + Bn;
constexpr size_t O_LOSS = O_IDX + BTn;
constexpr size_t O_PPL  = O_LOSS + 1;
} // namespace

__device__ __forceinline__ float nan0(float v) {
    return __builtin_isfinite(v) ? v : 0.0f;
}
__device__ __forceinline__ float dot4(float4 a, float4 b) {
    return a.x * b.x + a.y * b.y + a.z * b.z + a.w * b.w;
}

// ---------------------------------------------------------------- K0: zero counts + codebook row norms
__global__ __launch_bounds__(256) void k_esq_zero(const float* __restrict__ cb,
                                                  float* __restrict__ e_sq,
                                                  int* __restrict__ counts) {
    int i = blockIdx.x * 256 + threadIdx.x;
    if (i < Kn) {
        counts[i] = 0;
        const float4* r = (const float4*)(cb + (size_t)i * EMBn);
        float s = 0.f;
#pragma unroll
        for (int j = 0; j < 16; ++j) { float4 v = r[j]; s += dot4(v, v); }
        e_sq[i] = s;
    }
}

// ---------------------------------------------------------------- K1: naip conv + proj -> naip2 (B x HID)
__global__ __launch_bounds__(128) void k_naip(const float* __restrict__ naip,
                                              const float* __restrict__ conv_w,
                                              const float* __restrict__ conv_b,
                                              const float* __restrict__ pw,
                                              const float* __restrict__ pb,
                                              float* __restrict__ naip2) {
    int b = blockIdx.x, o = threadIdx.x;
    __shared__ float feat[HIDn];
    float acc = conv_b[o];
#pragma unroll
    for (int i = 0; i < 9; ++i) acc += nan0(naip[b * 9 + i]) * conv_w[o * 9 + i];
    feat[o] = fmaxf(acc, 0.f);
    __syncthreads();
    float a2 = pb[o];
    const float4* wr = (const float4*)(pw + (size_t)o * HIDn);
    const float4* fr = (const float4*)feat;
#pragma unroll
    for (int j = 0; j < 32; ++j) a2 += dot4(fr[j], wr[j]);
    naip2[(size_t)b * HIDn + o] = a2;
}

// ---------------------------------------------------------------- K2: fused inputs -> z_e (BT x EMB)
__global__ __launch_bounds__(256) void k_ze(
    const float* __restrict__ cont, const int* __restrict__ cat,
    const float* __restrict__ emb_sp, const float* __restrict__ emb_lc,
    const float* __restrict__ cpw, const float* __restrict__ cpb,
    const float* __restrict__ caw, const float* __restrict__ cab,
    const float* __restrict__ f1w, const float* __restrict__ f1b,
    const float* __restrict__ f2w, const float* __restrict__ f2b,
    const float* __restrict__ naip2, float* __restrict__ z_e) {
    const int tok0 = blockIdx.x * 16;
    const int tid = threadIdx.x;
    __shared__ float fused[16][FINn + 4]; // stride 388 floats
    __shared__ float h1[16][HIDn + 4];    // stride 132

    for (int idx = tid; idx < 16 * HIDn; idx += 256) {
        int t = idx >> 7, j = idx & 127;
        int b = (tok0 + t) / Tn;
        fused[t][j] = naip2[(size_t)b * HIDn + j];
    }
    for (int idx = tid; idx < 16 * HIDn; idx += 256) {
        int t = idx >> 7, o = idx & 127;
        int tok = tok0 + t;
        const float4* cp = (const float4*)(cont + (size_t)tok * CONTn);
        const float4* wr = (const float4*)(cpw + (size_t)o * CONTn);
        float a = cpb[o];
#pragma unroll
        for (int q = 0; q < 4; ++q) {
            float4 c4 = cp[q], w4 = wr[q];
            a += nan0(c4.x) * w4.x + nan0(c4.y) * w4.y + nan0(c4.z) * w4.z + nan0(c4.w) * w4.w;
        }
        fused[t][HIDn + o] = a;
    }
    for (int idx = tid; idx < 16 * HIDn; idx += 256) {
        int t = idx >> 7, o = idx & 127;
        int tok = tok0 + t;
        int c0 = cat[tok * 2], c1 = cat[tok * 2 + 1];
        const float* e0 = emb_sp + (size_t)c0 * CEn;
        const float* e1 = emb_lc + (size_t)c1 * CEn;
        const float* wr = caw + (size_t)o * (2 * CEn);
        float a = cab[o];
#pragma unroll
        for (int i = 0; i < CEn; ++i) a += e0[i] * wr[i];
#pragma unroll
        for (int i = 0; i < CEn; ++i) a += e1[i] * wr[CEn + i];
        fused[t][2 * HIDn + o] = a;
    }
    __syncthreads();
    {
        int o = tid >> 1, half = tid & 1;
        float acc[8];
        float bv = f1b[o];
#pragma unroll
        for (int t = 0; t < 8; ++t) acc[t] = bv;
        const float4* wr = (const float4*)(f1w + (size_t)o * FINn);
        for (int kk = 0; kk < FINn / 4; ++kk) {
            float4 w = wr[kk];
#pragma unroll
            for (int t = 0; t < 8; ++t) {
                float4 f = ((const float4*)&fused[half * 8 + t][0])[kk];
                acc[t] += dot4(f, w);
            }
        }
#pragma unroll
        for (int t = 0; t < 8; ++t) h1[half * 8 + t][o] = fmaxf(acc[t], 0.f);
    }
    __syncthreads();
    {
        int o = tid & 63, tg = tid >> 6;
        float acc[4];
        float bv = f2b[o];
#pragma unroll
        for (int t = 0; t < 4; ++t) acc[t] = bv;
        const float4* wr = (const float4*)(f2w + (size_t)o * HIDn);
        for (int kk = 0; kk < HIDn / 4; ++kk) {
            float4 w = wr[kk];
#pragma unroll
            for (int t = 0; t < 4; ++t) {
                float4 f = ((const float4*)&h1[tg * 4 + t][0])[kk];
                acc[t] += dot4(f, w);
            }
        }
#pragma unroll
        for (int t = 0; t < 4; ++t) z_e[(size_t)(tok0 + tg * 4 + t) * EMBn + o] = acc[t];
    }
}

// ---------------------------------------------------------------- K3a: VQ partial argmin over a 1024-code chunk
// grid (VQ_CHUNKS, BT/128); block 256: x=tid&7 (8 code cols), y=tid>>3 (32 tok rows x 4 toks)
struct alignas(16) VqShared {
    union {
        float ct[64][68];
        struct { float rd[128][8]; int ri[128][8]; } r;
    } u;
};

__global__ __launch_bounds__(256) void k_vq_partial(
    const float* __restrict__ z_e, const float* __restrict__ cb,
    const float* __restrict__ e_sq, float* __restrict__ pd, int* __restrict__ pi) {
    const int tid = threadIdx.x;
    const int x = tid & 7;
    const int y = tid >> 3;
    const int chunk = blockIdx.x;
    const int c_base = chunk * (Kn / VQ_CHUNKS);
    const int tok0 = blockIdx.y * VQ_TOK;

    __shared__ float zt[VQ_TOK][68];
    __shared__ VqShared s;
    __shared__ float es[64];

    for (int idx = tid; idx < VQ_TOK * 16; idx += 256) {
        int t = idx >> 4, q = idx & 15;
        ((float4*)&zt[t][0])[q] = ((const float4*)(z_e + (size_t)(tok0 + t) * EMBn))[q];
    }

    float bd[4];
    int bi[4];
#pragma unroll
    for (int t = 0; t < 4; ++t) { bd[t] = INFINITY; bi[t] = 0; }

    for (int tile = 0; tile < (Kn / VQ_CHUNKS) / 64; ++tile) { // 16 tiles of 64 codes
        const int c0 = c_base + tile * 64;
        __syncthreads();
        for (int idx = tid; idx < 64 * 16; idx += 256) {
            int c = idx >> 4, q = idx & 15;
            ((float4*)&s.u.ct[c][0])[q] = ((const float4*)(cb + (size_t)(c0 + c) * EMBn))[q];
        }
        if (tid < 64) es[tid] = e_sq[c0 + tid];
        __syncthreads();

        float acc[4][8];
#pragma unroll
        for (int t = 0; t < 4; ++t)
#pragma unroll
            for (int j = 0; j < 8; ++j) acc[t][j] = 0.f;

#pragma unroll
        for (int kk = 0; kk < 16; ++kk) {
            float4 zz[4];
#pragma unroll
            for (int t = 0; t < 4; ++t) zz[t] = ((const float4*)&zt[y * 4 + t][0])[kk];
#pragma unroll
            for (int j = 0; j < 8; ++j) {
                float4 c4 = ((const float4*)&s.u.ct[x + 8 * j][0])[kk];
#pragma unroll
                for (int t = 0; t < 4; ++t) acc[t][j] += dot4(zz[t], c4);
            }
        }
#pragma unroll
        for (int j = 0; j < 8; ++j) {
            int c = c0 + x + 8 * j;
            float e = es[x + 8 * j];
#pragma unroll
            for (int t = 0; t < 4; ++t) {
                float d = e - 2.f * acc[t][j];
                if (d < bd[t]) { bd[t] = d; bi[t] = c; } // codes ascending per thread
            }
        }
    }
    __syncthreads(); // done with ct; reuse as reduce arrays
#pragma unroll
    for (int t = 0; t < 4; ++t) { s.u.r.rd[y * 4 + t][x] = bd[t]; s.u.r.ri[y * 4 + t][x] = bi[t]; }
    __syncthreads();
    if (tid < VQ_TOK) {
        float best = s.u.r.rd[tid][0];
        int b_ = s.u.r.ri[tid][0];
#pragma unroll
        for (int xx = 1; xx < 8; ++xx) {
            float d = s.u.r.rd[tid][xx];
            int i2 = s.u.r.ri[tid][xx];
            if (d < best || (d == best && i2 < b_)) { best = d; b_ = i2; }
        }
        pd[(size_t)chunk * BTn + tok0 + tid] = best;
        pi[(size_t)chunk * BTn + tok0 + tid] = b_;
    }
}

// ---------------------------------------------------------------- K3b: merge chunks, gather z_q, counts, loss
__global__ __launch_bounds__(256) void k_vq_reduce(
    const float* __restrict__ pd, const int* __restrict__ pi,
    const float* __restrict__ z_e, const float* __restrict__ cb,
    float* __restrict__ z_q, float* __restrict__ idx_out,
    int* __restrict__ counts, float* __restrict__ partials) {
    const int tid = threadIdx.x;
    const int tok = blockIdx.x * 256 + tid;
    float best = pd[tok];
    int b_ = pi[tok];
#pragma unroll
    for (int c = 1; c < VQ_CHUNKS; ++c) {
        float d = pd[(size_t)c * BTn + tok];
        int i2 = pi[(size_t)c * BTn + tok];
        if (d < best || (d == best && i2 < b_)) { best = d; b_ = i2; }
    }
    idx_out[tok] = (float)b_;
    atomicAdd(&counts[b_], 1);

    float lsum = 0.f;
    const float4* cr = (const float4*)(cb + (size_t)b_ * EMBn);
    const float4* zr = (const float4*)(z_e + (size_t)tok * EMBn);
    float4* qr = (float4*)(z_q + (size_t)tok * EMBn);
#pragma unroll
    for (int q = 0; q < 16; ++q) {
        float4 cq = cr[q];
        qr[q] = cq;
        float4 zz = zr[q];
        float dx = zz.x - cq.x, dy = zz.y - cq.y, dz = zz.z - cq.z, dw = zz.w - cq.w;
        lsum += dx * dx + dy * dy + dz * dz + dw * dw;
    }
    __shared__ float red[256];
    red[tid] = lsum;
    __syncthreads();
    for (int sdist = 128; sdist > 0; sdist >>= 1) {
        if (tid < sdist) red[tid] += red[tid + sdist];
        __syncthreads();
    }
    if (tid == 0) partials[blockIdx.x] = red[0];
}

// ---------------------------------------------------------------- K4: backbone + small heads
__global__ __launch_bounds__(256) void k_backbone(
    const float* __restrict__ z_q,
    const float* __restrict__ bb1w, const float* __restrict__ bb1b,
    const float* __restrict__ bb2w, const float* __restrict__ bb2b,
    const float* __restrict__ chw, const float* __restrict__ chb,
    const float* __restrict__ lcw, const float* __restrict__ lcb,
    float* __restrict__ h_out, float* __restrict__ cont_rec, float* __restrict__ lc_out) {
    const int tid = threadIdx.x;
    const int tok0 = blockIdx.x * 16;
    __shared__ float zq[16][68];
    __shared__ float h1[16][HIDn + 4];
    __shared__ float h2[16][HIDn + 4];
    {
        int t = tid >> 4, q = tid & 15;
        ((float4*)&zq[t][0])[q] = ((const float4*)(z_q + (size_t)(tok0 + t) * EMBn))[q];
    }
    __syncthreads();
    {
        int o = tid >> 1, half = tid & 1;
        float acc[8];
        float bv = bb1b[o];
#pragma unroll
        for (int t = 0; t < 8; ++t) acc[t] = bv;
        const float4* wr = (const float4*)(bb1w + (size_t)o * EMBn);
#pragma unroll
        for (int kk = 0; kk < 16; ++kk) {
            float4 w = wr[kk];
#pragma unroll
            for (int t = 0; t < 8; ++t) acc[t] += dot4(((const float4*)&zq[half * 8 + t][0])[kk], w);
        }
#pragma unroll
        for (int t = 0; t < 8; ++t) h1[half * 8 + t][o] = fmaxf(acc[t], 0.f);
    }
    __syncthreads();
    {
        int o = tid >> 1, half = tid & 1;
        float acc[8];
        float bv = bb2b[o];
#pragma unroll
        for (int t = 0; t < 8; ++t) acc[t] = bv;
        const float4* wr = (const float4*)(bb2w + (size_t)o * HIDn);
        for (int kk = 0; kk < 32; ++kk) {
            float4 w = wr[kk];
#pragma unroll
            for (int t = 0; t < 8; ++t) acc[t] += dot4(((const float4*)&h1[half * 8 + t][0])[kk], w);
        }
#pragma unroll
        for (int t = 0; t < 8; ++t) {
            float v = fmaxf(acc[t], 0.f);
            h2[half * 8 + t][o] = v;
            h_out[(size_t)(tok0 + half * 8 + t) * HIDn + o] = v;
        }
    }
    __syncthreads();
    {
        int t = tid >> 4, o = tid & 15;
        float a = chb[o];
        const float4* wr = (const float4*)(chw + (size_t)o * HIDn);
#pragma unroll
        for (int kk = 0; kk < 32; ++kk) a += dot4(((const float4*)&h2[t][0])[kk], wr[kk]);
        cont_rec[(size_t)(tok0 + t) * CONTn + o] = a;
    }
    for (int idx = tid; idx < 16 * 32; idx += 256) {
        int t = idx >> 5, o = idx & 31;
        float a = lcb[o];
        const float4* wr = (const float4*)(lcw + (size_t)o * HIDn);
#pragma unroll
        for (int kk = 0; kk < 32; ++kk) a += dot4(((const float4*)&h2[t][0])[kk], wr[kk]);
        lc_out[(size_t)(tok0 + t) * VLCn + o] = a;
    }
}

// ---------------------------------------------------------------- K5: sp_logits GEMM (16384x128)@(128->2000)
__global__ __launch_bounds__(256) void k_sp(const float* __restrict__ h,
                                            const float* __restrict__ w,
                                            const float* __restrict__ bias,
                                            float* __restrict__ out) {
    const int tid = threadIdx.x;
    const int x = tid & 15, y = tid >> 4;
    const int v0 = blockIdx.x * 128;
    const int tok0 = blockIdx.y * 128;
    __shared__ float ht[128][36];
    __shared__ float wt[128][36];
    float acc[8][8];
#pragma unroll
    for (int t = 0; t < 8; ++t)
#pragma unroll
        for (int j = 0; j < 8; ++j) acc[t][j] = 0.f;

    for (int kq = 0; kq < 4; ++kq) {
        __syncthreads();
        for (int idx = tid; idx < 128 * 8; idx += 256) {
            int t = idx >> 3, q = idx & 7;
            ((float4*)&ht[t][0])[q] = ((const float4*)(h + (size_t)(tok0 + t) * HIDn + kq * 32))[q];
        }
        for (int idx = tid; idx < 128 * 8; idx += 256) {
            int r = idx >> 3, q = idx & 7;
            int v = v0 + r;
            float4 val = make_float4(0.f, 0.f, 0.f, 0.f);
            if (v < VSPn) val = ((const float4*)(w + (size_t)v * HIDn + kq * 32))[q];
            ((float4*)&wt[r][0])[q] = val;
        }
        __syncthreads();
#pragma unroll
        for (int kk = 0; kk < 8; ++kk) {
            float4 hh[8];
#pragma unroll
            for (int t = 0; t < 8; ++t) hh[t] = ((const float4*)&ht[y * 8 + t][0])[kk];
#pragma unroll
            for (int j = 0; j < 8; ++j) {
                float4 ww = ((const float4*)&wt[x + 16 * j][0])[kk];
#pragma unroll
                for (int t = 0; t < 8; ++t) acc[t][j] += dot4(hh[t], ww);
            }
        }
    }
#pragma unroll
    for (int j = 0; j < 8; ++j) {
        int v = v0 + x + 16 * j;
        if (v < VSPn) {
            float bv = bias[v];
#pragma unroll
            for (int t = 0; t < 8; ++t)
                out[(size_t)(tok0 + y * 8 + t) * VSPn + v] = acc[t][j] + bv;
        }
    }
}

// ---------------------------------------------------------------- K6: canopy head on h[:, -1, :]
__global__ __launch_bounds__(128) void k_canopy(const float* __restrict__ h,
                                                const float* __restrict__ w1,
                                                const float* __restrict__ b1,
                                                const float* __restrict__ w2,
                                                const float* __restrict__ b2,
                                                float* __restrict__ can) {
    int b = blockIdx.x, o = threadIdx.x;
    __shared__ float r[128];
    const float4* hr = (const float4*)(h + (size_t)(b * Tn + Tn - 1) * HIDn);
    const float4* wr = (const float4*)(w1 + (size_t)o * HIDn);
    float a = b1[o];
#pragma unroll
    for (int kk = 0; kk < 32; ++kk) a += dot4(hr[kk], wr[kk]);
    r[o] = fmaxf(a, 0.f) * w2[o];
    __syncthreads();
    for (int s = 64; s > 0; s >>= 1) {
        if (o < s) r[o] += r[o + s];
        __syncthreads();
    }
    if (o == 0) can[b] = r[0] + b2[0];
}

// ---------------------------------------------------------------- K7: loss + perplexity
__global__ __launch_bounds__(256) void k_finalize(const float* __restrict__ partials,
                                                  const int* __restrict__ counts,
                                                  float* __restrict__ out_loss,
                                                  float* __restrict__ out_ppl) {
    const int tid = threadIdx.x;
    __shared__ float red[256];
    red[tid] = (tid < 64) ? partials[tid] : 0.f;
    __syncthreads();
    for (int s = 128; s > 0; s >>= 1) {
        if (tid < s) red[tid] += red[tid + s];
        __syncthreads();
    }
    float total = red[0];
    __syncthreads();
    float e = 0.f;
    for (int i = tid; i < Kn; i += 256) {
        float p = (float)counts[i] * (1.0f / BTn);
        e += p * logf(p + 1e-12f);
    }
    red[tid] = e;
    __syncthreads();
    for (int s = 128; s > 0; s >>= 1) {
        if (tid < s) red[tid] += red[tid + s];
        __syncthreads();
    }
    if (tid == 0) {
        out_loss[0] = 1.25f * total / (float)((size_t)BTn * EMBn);
        out_ppl[0] = expf(-red[0]);
    }
}

// ----------------------------------------------------------------
extern "C" void kernel_launch(void* const* d_in, const int* in_sizes, int n_in,
                              void* d_out, int out_size, void* d_ws, size_t ws_size,
                              hipStream_t stream) {
    const float* cont = (const float*)d_in[0];
    const float* naip = (const float*)d_in[1];
    const int* cat = (const int*)d_in[2];
    const float* emb_sp = (const float*)d_in[3];
    const float* emb_lc = (const float*)d_in[4];
    const float* conv_w = (const float*)d_in[5];
    const float* conv_b = (const float*)d_in[6];
    const float* npw = (const float*)d_in[7];
    const float* npb = (const float*)d_in[8];
    const float* cpw = (const float*)d_in[9];
    const float* cpb = (const float*)d_in[10];
    const float* caw = (const float*)d_in[11];
    const float* cab = (const float*)d_in[12];
    const float* f1w = (const float*)d_in[13];
    const float* f1b = (const float*)d_in[14];
    const float* f2w = (const float*)d_in[15];
    const float* f2b = (const float*)d_in[16];
    const float* cb = (const float*)d_in[17];
    const float* bb1w = (const float*)d_in[18];
    const float* bb1b = (const float*)d_in[19];
    const float* bb2w = (const float*)d_in[20];
    const float* bb2b = (const float*)d_in[21];
    const float* chw = (const float*)d_in[22];
    const float* chb = (const float*)d_in[23];
    const float* spw = (const float*)d_in[24];
    const float* spb = (const float*)d_in[25];
    const float* lcw = (const float*)d_in[26];
    const float* lcb = (const float*)d_in[27];
    const float* c1w = (const float*)d_in[28];
    const float* c1b = (const float*)d_in[29];
    const float* c2w = (const float*)d_in[30];
    const float* c2b = (const float*)d_in[31];

    float* out = (float*)d_out;
    float* ws = (float*)d_ws;
    float* naip2 = ws + WS_NAIP2;
    float* z_e = ws + WS_ZE;
    float* z_q = ws + WS_ZQ;
    float* h = ws + WS_H;
    float* e_sq = ws + WS_ESQ;
    float* parts = ws + WS_PART;
    int* counts = (int*)(ws + WS_CNT);
    float* pd = ws + WS_PD;
    int* pi = (int*)(ws + WS_PI);

    k_esq_zero<<<dim3(Kn / 256), dim3(256), 0, stream>>>(cb, e_sq, counts);
    k_naip<<<dim3(Bn), dim3(128), 0, stream>>>(naip, conv_w, conv_b, npw, npb, naip2);
    k_ze<<<dim3(BTn / 16), dim3(256), 0, stream>>>(cont, cat, emb_sp, emb_lc, cpw, cpb, caw, cab,
                                                   f1w, f1b, f2w, f2b, naip2, z_e);
    k_vq_partial<<<dim3(VQ_CHUNKS, BTn / VQ_TOK), dim3(256), 0, stream>>>(z_e, cb, e_sq, pd, pi);
    k_vq_reduce<<<dim3(BTn / 256), dim3(256), 0, stream>>>(pd, pi, z_e, cb, z_q, out + O_IDX,
                                                           counts, parts);
    k_backbone<<<dim3(BTn / 16), dim3(256), 0, stream>>>(z_q, bb1w, bb1b, bb2w, bb2b, chw, chb,
                                                         lcw, lcb, h, out + O_CONT, out + O_LC);
    k_sp<<<dim3(16, BTn / 128), dim3(256), 0, stream>>>(h, spw, spb, out + O_SP);
    k_canopy<<<dim3(Bn), dim3(128), 0, stream>>>(h, c1w, c1b, c2w, c2b, out + O_CAN);
    k_finalize<<<dim3(1), dim3(256), 0, stream>>>(parts, counts, out + O_LOSS, out + O_PPL);
}

// Round 3
// 741.434 us; speedup vs baseline: 2.0462x; 1.0447x over previous
//
#include <hip/hip_runtime.h>
#include <cmath>

namespace {
constexpr int Bn = 128, Tn = 128, BTn = Bn * Tn;
constexpr int CONTn = 16, HIDn = 128, EMBn = 64;
constexpr int Kn = 8192, CEn = 6, VSPn = 2000, VLCn = 32, FINn = 3 * HIDn;
constexpr int VQ_CHUNKS = 16;             // 512 codes per chunk
constexpr int VQ_TOK = 128;               // tokens per block

// ---- workspace layout (float units) ----
constexpr size_t WS_NAIP2 = 0;                               // B*HID
constexpr size_t WS_ZE    = WS_NAIP2 + (size_t)Bn * HIDn;    // BT*EMB
constexpr size_t WS_ZQ    = WS_ZE + (size_t)BTn * EMBn;      // BT*EMB
constexpr size_t WS_H     = WS_ZQ + (size_t)BTn * EMBn;      // BT*HID
constexpr size_t WS_ESQ   = WS_H + (size_t)BTn * HIDn;       // K
constexpr size_t WS_PART  = WS_ESQ + Kn;                     // 64 partial loss sums
constexpr size_t WS_CNT   = WS_PART + 64;                    // K ints
constexpr size_t WS_PD    = WS_CNT + Kn;                     // VQ_CHUNKS*BT floats
constexpr size_t WS_PI    = WS_PD + (size_t)VQ_CHUNKS * BTn; // VQ_CHUNKS*BT ints

// ---- output layout (float units) ----
constexpr size_t O_CONT = 0;
constexpr size_t O_SP   = O_CONT + (size_t)BTn * CONTn;
constexpr size_t O_LC   = O_SP + (size_t)BTn * VSPn;
constexpr size_t O_CAN  = O_LC + (size_t)BTn * VLCn;
constexpr size_t O_IDX  = O_CAN + Bn;
constexpr size_t O_LOSS = O_IDX + BTn;
constexpr size_t O_PPL  = O_LOSS + 1;
} // namespace

__device__ __forceinline__ float nan0(float v) {
    return __builtin_isfinite(v) ? v : 0.0f;
}
__device__ __forceinline__ float dot4(float4 a, float4 b) {
    return a.x * b.x + a.y * b.y + a.z * b.z + a.w * b.w;
}

// ---------------------------------------------------------------- K0: zero counts + codebook row norms
__global__ __launch_bounds__(256) void k_esq_zero(const float* __restrict__ cb,
                                                  float* __restrict__ e_sq,
                                                  int* __restrict__ counts) {
    int i = blockIdx.x * 256 + threadIdx.x;
    if (i < Kn) {
        counts[i] = 0;
        const float4* r = (const float4*)(cb + (size_t)i * EMBn);
        float s = 0.f;
#pragma unroll
        for (int j = 0; j < 16; ++j) { float4 v = r[j]; s += dot4(v, v); }
        e_sq[i] = s;
    }
}

// ---------------------------------------------------------------- K1: naip conv + proj -> naip2 (B x HID)
__global__ __launch_bounds__(128) void k_naip(const float* __restrict__ naip,
                                              const float* __restrict__ conv_w,
                                              const float* __restrict__ conv_b,
                                              const float* __restrict__ pw,
                                              const float* __restrict__ pb,
                                              float* __restrict__ naip2) {
    int b = blockIdx.x, o = threadIdx.x;
    __shared__ float feat[HIDn];
    float acc = conv_b[o];
#pragma unroll
    for (int i = 0; i < 9; ++i) acc += nan0(naip[b * 9 + i]) * conv_w[o * 9 + i];
    feat[o] = fmaxf(acc, 0.f);
    __syncthreads();
    float a2 = pb[o];
    const float4* wr = (const float4*)(pw + (size_t)o * HIDn);
    const float4* fr = (const float4*)feat;
#pragma unroll
    for (int j = 0; j < 32; ++j) a2 += dot4(fr[j], wr[j]);
    naip2[(size_t)b * HIDn + o] = a2;
}

// ---------------------------------------------------------------- K2: fused inputs -> z_e (BT x EMB)
__global__ __launch_bounds__(256) void k_ze(
    const float* __restrict__ cont, const int* __restrict__ cat,
    const float* __restrict__ emb_sp, const float* __restrict__ emb_lc,
    const float* __restrict__ cpw, const float* __restrict__ cpb,
    const float* __restrict__ caw, const float* __restrict__ cab,
    const float* __restrict__ f1w, const float* __restrict__ f1b,
    const float* __restrict__ f2w, const float* __restrict__ f2b,
    const float* __restrict__ naip2, float* __restrict__ z_e) {
    const int tok0 = blockIdx.x * 16;
    const int tid = threadIdx.x;
    __shared__ float fused[16][FINn + 4]; // stride 388 floats
    __shared__ float h1[16][HIDn + 4];    // stride 132

    for (int idx = tid; idx < 16 * HIDn; idx += 256) {
        int t = idx >> 7, j = idx & 127;
        int b = (tok0 + t) / Tn;
        fused[t][j] = naip2[(size_t)b * HIDn + j];
    }
    for (int idx = tid; idx < 16 * HIDn; idx += 256) {
        int t = idx >> 7, o = idx & 127;
        int tok = tok0 + t;
        const float4* cp = (const float4*)(cont + (size_t)tok * CONTn);
        const float4* wr = (const float4*)(cpw + (size_t)o * CONTn);
        float a = cpb[o];
#pragma unroll
        for (int q = 0; q < 4; ++q) {
            float4 c4 = cp[q], w4 = wr[q];
            a += nan0(c4.x) * w4.x + nan0(c4.y) * w4.y + nan0(c4.z) * w4.z + nan0(c4.w) * w4.w;
        }
        fused[t][HIDn + o] = a;
    }
    for (int idx = tid; idx < 16 * HIDn; idx += 256) {
        int t = idx >> 7, o = idx & 127;
        int tok = tok0 + t;
        int c0 = cat[tok * 2], c1 = cat[tok * 2 + 1];
        const float* e0 = emb_sp + (size_t)c0 * CEn;
        const float* e1 = emb_lc + (size_t)c1 * CEn;
        const float* wr = caw + (size_t)o * (2 * CEn);
        float a = cab[o];
#pragma unroll
        for (int i = 0; i < CEn; ++i) a += e0[i] * wr[i];
#pragma unroll
        for (int i = 0; i < CEn; ++i) a += e1[i] * wr[CEn + i];
        fused[t][2 * HIDn + o] = a;
    }
    __syncthreads();
    {
        int o = tid >> 1, half = tid & 1;
        float acc[8];
        float bv = f1b[o];
#pragma unroll
        for (int t = 0; t < 8; ++t) acc[t] = bv;
        const float4* wr = (const float4*)(f1w + (size_t)o * FINn);
        for (int kk = 0; kk < FINn / 4; ++kk) {
            float4 w = wr[kk];
#pragma unroll
            for (int t = 0; t < 8; ++t) {
                float4 f = ((const float4*)&fused[half * 8 + t][0])[kk];
                acc[t] += dot4(f, w);
            }
        }
#pragma unroll
        for (int t = 0; t < 8; ++t) h1[half * 8 + t][o] = fmaxf(acc[t], 0.f);
    }
    __syncthreads();
    {
        int o = tid & 63, tg = tid >> 6;
        float acc[4];
        float bv = f2b[o];
#pragma unroll
        for (int t = 0; t < 4; ++t) acc[t] = bv;
        const float4* wr = (const float4*)(f2w + (size_t)o * HIDn);
        for (int kk = 0; kk < HIDn / 4; ++kk) {
            float4 w = wr[kk];
#pragma unroll
            for (int t = 0; t < 4; ++t) {
                float4 f = ((const float4*)&h1[tg * 4 + t][0])[kk];
                acc[t] += dot4(f, w);
            }
        }
#pragma unroll
        for (int t = 0; t < 4; ++t) z_e[(size_t)(tok0 + tg * 4 + t) * EMBn + o] = acc[t];
    }
}

// ---------------------------------------------------------------- K3a: VQ partial argmin over a 512-code chunk
// grid (VQ_CHUNKS, BT/128); block 256: x=tid&15 (16 code groups x 8 codes = 128 codes/tile),
// y=tid>>4 (16 token groups x 8 toks = 128 toks). Per-thread 8x8 f32 tile.
// LDS XOR-swizzle (T2): zt col4 ^= row>>3 ; ct col4 ^= row&15 (same involution on write+read).
struct alignas(16) VqShared {
    union {
        float ct[128][64];
        struct { float rd[128][17]; int ri[128][17]; } r;
    } u;
};

__global__ __launch_bounds__(256, 2) void k_vq_partial(
    const float* __restrict__ z_e, const float* __restrict__ cb,
    const float* __restrict__ e_sq, float* __restrict__ pd, int* __restrict__ pi) {
    const int tid = threadIdx.x;
    const int x = tid & 15;
    const int y = tid >> 4;
    const int chunk = blockIdx.x;
    const int c_base = chunk * (Kn / VQ_CHUNKS);
    const int tok0 = blockIdx.y * VQ_TOK;

    __shared__ float zt[VQ_TOK][64];
    __shared__ VqShared s;
    __shared__ float es[128];

    // stage z tile once (swizzled)
    for (int idx = tid; idx < VQ_TOK * 16; idx += 256) {
        int t = idx >> 4, q = idx & 15;
        ((float4*)&zt[t][0])[q ^ (t >> 3)] =
            ((const float4*)(z_e + (size_t)(tok0 + t) * EMBn))[q];
    }

    float bd[8];
    int bi[8];
#pragma unroll
    for (int t = 0; t < 8; ++t) { bd[t] = INFINITY; bi[t] = 0; }

    for (int tile = 0; tile < (Kn / VQ_CHUNKS) / 128; ++tile) { // 4 tiles of 128 codes
        const int c0 = c_base + tile * 128;
        __syncthreads();
        for (int idx = tid; idx < 128 * 16; idx += 256) {
            int c = idx >> 4, q = idx & 15;
            ((float4*)&s.u.ct[c][0])[q ^ (c & 15)] =
                ((const float4*)(cb + (size_t)(c0 + c) * EMBn))[q];
        }
        if (tid < 128) es[tid] = e_sq[c0 + tid];
        __syncthreads();

        float acc[8][8]; // [tok][code]
#pragma unroll
        for (int t = 0; t < 8; ++t)
#pragma unroll
            for (int j = 0; j < 8; ++j) acc[t][j] = 0.f;

#pragma unroll 4
        for (int kk = 0; kk < 16; ++kk) {
            float4 zz[8];
#pragma unroll
            for (int t = 0; t < 8; ++t)
                zz[t] = ((const float4*)&zt[y * 8 + t][0])[kk ^ y];
#pragma unroll
            for (int j = 0; j < 8; ++j) {
                float4 c4 = ((const float4*)&s.u.ct[x + 16 * j][0])[kk ^ x];
#pragma unroll
                for (int t = 0; t < 8; ++t) acc[t][j] += dot4(zz[t], c4);
            }
        }
#pragma unroll
        for (int j = 0; j < 8; ++j) {
            int c = c0 + x + 16 * j;
            float e = es[x + 16 * j];
#pragma unroll
            for (int t = 0; t < 8; ++t) {
                float d = e - 2.f * acc[t][j];
                if (d < bd[t]) { bd[t] = d; bi[t] = c; } // codes ascending per thread
            }
        }
    }
    __syncthreads(); // done with ct; reuse as reduce arrays
#pragma unroll
    for (int t = 0; t < 8; ++t) { s.u.r.rd[y * 8 + t][x] = bd[t]; s.u.r.ri[y * 8 + t][x] = bi[t]; }
    __syncthreads();
    if (tid < VQ_TOK) {
        float best = s.u.r.rd[tid][0];
        int b_ = s.u.r.ri[tid][0];
#pragma unroll
        for (int xx = 1; xx < 16; ++xx) {
            float d = s.u.r.rd[tid][xx];
            int i2 = s.u.r.ri[tid][xx];
            if (d < best || (d == best && i2 < b_)) { best = d; b_ = i2; }
        }
        pd[(size_t)chunk * BTn + tok0 + tid] = best;
        pi[(size_t)chunk * BTn + tok0 + tid] = b_;
    }
}

// ---------------------------------------------------------------- K3b: merge chunks, gather z_q, counts, loss
__global__ __launch_bounds__(256) void k_vq_reduce(
    const float* __restrict__ pd, const int* __restrict__ pi,
    const float* __restrict__ z_e, const float* __restrict__ cb,
    float* __restrict__ z_q, float* __restrict__ idx_out,
    int* __restrict__ counts, float* __restrict__ partials) {
    const int tid = threadIdx.x;
    const int tok = blockIdx.x * 256 + tid;
    float best = pd[tok];
    int b_ = pi[tok];
#pragma unroll
    for (int c = 1; c < VQ_CHUNKS; ++c) {
        float d = pd[(size_t)c * BTn + tok];
        int i2 = pi[(size_t)c * BTn + tok];
        if (d < best || (d == best && i2 < b_)) { best = d; b_ = i2; }
    }
    idx_out[tok] = (float)b_;
    atomicAdd(&counts[b_], 1);

    float lsum = 0.f;
    const float4* cr = (const float4*)(cb + (size_t)b_ * EMBn);
    const float4* zr = (const float4*)(z_e + (size_t)tok * EMBn);
    float4* qr = (float4*)(z_q + (size_t)tok * EMBn);
#pragma unroll
    for (int q = 0; q < 16; ++q) {
        float4 cq = cr[q];
        qr[q] = cq;
        float4 zz = zr[q];
        float dx = zz.x - cq.x, dy = zz.y - cq.y, dz = zz.z - cq.z, dw = zz.w - cq.w;
        lsum += dx * dx + dy * dy + dz * dz + dw * dw;
    }
    __shared__ float red[256];
    red[tid] = lsum;
    __syncthreads();
    for (int sdist = 128; sdist > 0; sdist >>= 1) {
        if (tid < sdist) red[tid] += red[tid + sdist];
        __syncthreads();
    }
    if (tid == 0) partials[blockIdx.x] = red[0];
}

// ---------------------------------------------------------------- K4: backbone + small heads
__global__ __launch_bounds__(256) void k_backbone(
    const float* __restrict__ z_q,
    const float* __restrict__ bb1w, const float* __restrict__ bb1b,
    const float* __restrict__ bb2w, const float* __restrict__ bb2b,
    const float* __restrict__ chw, const float* __restrict__ chb,
    const float* __restrict__ lcw, const float* __restrict__ lcb,
    float* __restrict__ h_out, float* __restrict__ cont_rec, float* __restrict__ lc_out) {
    const int tid = threadIdx.x;
    const int tok0 = blockIdx.x * 16;
    __shared__ float zq[16][68];
    __shared__ float h1[16][HIDn + 4];
    __shared__ float h2[16][HIDn + 4];
    {
        int t = tid >> 4, q = tid & 15;
        ((float4*)&zq[t][0])[q] = ((const float4*)(z_q + (size_t)(tok0 + t) * EMBn))[q];
    }
    __syncthreads();
    {
        int o = tid >> 1, half = tid & 1;
        float acc[8];
        float bv = bb1b[o];
#pragma unroll
        for (int t = 0; t < 8; ++t) acc[t] = bv;
        const float4* wr = (const float4*)(bb1w + (size_t)o * EMBn);
#pragma unroll
        for (int kk = 0; kk < 16; ++kk) {
            float4 w = wr[kk];
#pragma unroll
            for (int t = 0; t < 8; ++t) acc[t] += dot4(((const float4*)&zq[half * 8 + t][0])[kk], w);
        }
#pragma unroll
        for (int t = 0; t < 8; ++t) h1[half * 8 + t][o] = fmaxf(acc[t], 0.f);
    }
    __syncthreads();
    {
        int o = tid >> 1, half = tid & 1;
        float acc[8];
        float bv = bb2b[o];
#pragma unroll
        for (int t = 0; t < 8; ++t) acc[t] = bv;
        const float4* wr = (const float4*)(bb2w + (size_t)o * HIDn);
        for (int kk = 0; kk < 32; ++kk) {
            float4 w = wr[kk];
#pragma unroll
            for (int t = 0; t < 8; ++t) acc[t] += dot4(((const float4*)&h1[half * 8 + t][0])[kk], w);
        }
#pragma unroll
        for (int t = 0; t < 8; ++t) {
            float v = fmaxf(acc[t], 0.f);
            h2[half * 8 + t][o] = v;
            h_out[(size_t)(tok0 + half * 8 + t) * HIDn + o] = v;
        }
    }
    __syncthreads();
    {
        int t = tid >> 4, o = tid & 15;
        float a = chb[o];
        const float4* wr = (const float4*)(chw + (size_t)o * HIDn);
#pragma unroll
        for (int kk = 0; kk < 32; ++kk) a += dot4(((const float4*)&h2[t][0])[kk], wr[kk]);
        cont_rec[(size_t)(tok0 + t) * CONTn + o] = a;
    }
    for (int idx = tid; idx < 16 * 32; idx += 256) {
        int t = idx >> 5, o = idx & 31;
        float a = lcb[o];
        const float4* wr = (const float4*)(lcw + (size_t)o * HIDn);
#pragma unroll
        for (int kk = 0; kk < 32; ++kk) a += dot4(((const float4*)&h2[t][0])[kk], wr[kk]);
        lc_out[(size_t)(tok0 + t) * VLCn + o] = a;
    }
}

// ---------------------------------------------------------------- K5: sp_logits GEMM (16384x128)@(128->2000)
__global__ __launch_bounds__(256) void k_sp(const float* __restrict__ h,
                                            const float* __restrict__ w,
                                            const float* __restrict__ bias,
                                            float* __restrict__ out) {
    const int tid = threadIdx.x;
    const int x = tid & 15, y = tid >> 4;
    const int v0 = blockIdx.x * 128;
    const int tok0 = blockIdx.y * 128;
    __shared__ float ht[128][36];
    __shared__ float wt[128][36];
    float acc[8][8];
#pragma unroll
    for (int t = 0; t < 8; ++t)
#pragma unroll
        for (int j = 0; j < 8; ++j) acc[t][j] = 0.f;

    for (int kq = 0; kq < 4; ++kq) {
        __syncthreads();
        for (int idx = tid; idx < 128 * 8; idx += 256) {
            int t = idx >> 3, q = idx & 7;
            ((float4*)&ht[t][0])[q] = ((const float4*)(h + (size_t)(tok0 + t) * HIDn + kq * 32))[q];
        }
        for (int idx = tid; idx < 128 * 8; idx += 256) {
            int r = idx >> 3, q = idx & 7;
            int v = v0 + r;
            float4 val = make_float4(0.f, 0.f, 0.f, 0.f);
            if (v < VSPn) val = ((const float4*)(w + (size_t)v * HIDn + kq * 32))[q];
            ((float4*)&wt[r][0])[q] = val;
        }
        __syncthreads();
#pragma unroll
        for (int kk = 0; kk < 8; ++kk) {
            float4 hh[8];
#pragma unroll
            for (int t = 0; t < 8; ++t) hh[t] = ((const float4*)&ht[y * 8 + t][0])[kk];
#pragma unroll
            for (int j = 0; j < 8; ++j) {
                float4 ww = ((const float4*)&wt[x + 16 * j][0])[kk];
#pragma unroll
                for (int t = 0; t < 8; ++t) acc[t][j] += dot4(hh[t], ww);
            }
        }
    }
#pragma unroll
    for (int j = 0; j < 8; ++j) {
        int v = v0 + x + 16 * j;
        if (v < VSPn) {
            float bv = bias[v];
#pragma unroll
            for (int t = 0; t < 8; ++t)
                out[(size_t)(tok0 + y * 8 + t) * VSPn + v] = acc[t][j] + bv;
        }
    }
}

// ---------------------------------------------------------------- K6: canopy head on h[:, -1, :]
__global__ __launch_bounds__(128) void k_canopy(const float* __restrict__ h,
                                                const float* __restrict__ w1,
                                                const float* __restrict__ b1,
                                                const float* __restrict__ w2,
                                                const float* __restrict__ b2,
                                                float* __restrict__ can) {
    int b = blockIdx.x, o = threadIdx.x;
    __shared__ float r[128];
    const float4* hr = (const float4*)(h + (size_t)(b * Tn + Tn - 1) * HIDn);
    const float4* wr = (const float4*)(w1 + (size_t)o * HIDn);
    float a = b1[o];
#pragma unroll
    for (int kk = 0; kk < 32; ++kk) a += dot4(hr[kk], wr[kk]);
    r[o] = fmaxf(a, 0.f) * w2[o];
    __syncthreads();
    for (int s = 64; s > 0; s >>= 1) {
        if (o < s) r[o] += r[o + s];
        __syncthreads();
    }
    if (o == 0) can[b] = r[0] + b2[0];
}

// ---------------------------------------------------------------- K7: loss + perplexity
__global__ __launch_bounds__(256) void k_finalize(const float* __restrict__ partials,
                                                  const int* __restrict__ counts,
                                                  float* __restrict__ out_loss,
                                                  float* __restrict__ out_ppl) {
    const int tid = threadIdx.x;
    __shared__ float red[256];
    red[tid] = (tid < 64) ? partials[tid] : 0.f;
    __syncthreads();
    for (int s = 128; s > 0; s >>= 1) {
        if (tid < s) red[tid] += red[tid + s];
        __syncthreads();
    }
    float total = red[0];
    __syncthreads();
    float e = 0.f;
    for (int i = tid; i < Kn; i += 256) {
        float p = (float)counts[i] * (1.0f / BTn);
        e += p * logf(p + 1e-12f);
    }
    red[tid] = e;
    __syncthreads();
    for (int s = 128; s > 0; s >>= 1) {
        if (tid < s) red[tid] += red[tid + s];
        __syncthreads();
    }
    if (tid == 0) {
        out_loss[0] = 1.25f * total / (float)((size_t)BTn * EMBn);
        out_ppl[0] = expf(-red[0]);
    }
}

// ----------------------------------------------------------------
extern "C" void kernel_launch(void* const* d_in, const int* in_sizes, int n_in,
                              void* d_out, int out_size, void* d_ws, size_t ws_size,
                              hipStream_t stream) {
    const float* cont = (const float*)d_in[0];
    const float* naip = (const float*)d_in[1];
    const int* cat = (const int*)d_in[2];
    const float* emb_sp = (const float*)d_in[3];
    const float* emb_lc = (const float*)d_in[4];
    const float* conv_w = (const float*)d_in[5];
    const float* conv_b = (const float*)d_in[6];
    const float* npw = (const float*)d_in[7];
    const float* npb = (const float*)d_in[8];
    const float* cpw = (const float*)d_in[9];
    const float* cpb = (const float*)d_in[10];
    const float* caw = (const float*)d_in[11];
    const float* cab = (const float*)d_in[12];
    const float* f1w = (const float*)d_in[13];
    const float* f1b = (const float*)d_in[14];
    const float* f2w = (const float*)d_in[15];
    const float* f2b = (const float*)d_in[16];
    const float* cb = (const float*)d_in[17];
    const float* bb1w = (const float*)d_in[18];
    const float* bb1b = (const float*)d_in[19];
    const float* bb2w = (const float*)d_in[20];
    const float* bb2b = (const float*)d_in[21];
    const float* chw = (const float*)d_in[22];
    const float* chb = (const float*)d_in[23];
    const float* spw = (const float*)d_in[24];
    const float* spb = (const float*)d_in[25];
    const float* lcw = (const float*)d_in[26];
    const float* lcb = (const float*)d_in[27];
    const float* c1w = (const float*)d_in[28];
    const float* c1b = (const float*)d_in[29];
    const float* c2w = (const float*)d_in[30];
    const float* c2b = (const float*)d_in[31];

    float* out = (float*)d_out;
    float* ws = (float*)d_ws;
    float* naip2 = ws + WS_NAIP2;
    float* z_e = ws + WS_ZE;
    float* z_q = ws + WS_ZQ;
    float* h = ws + WS_H;
    float* e_sq = ws + WS_ESQ;
    float* parts = ws + WS_PART;
    int* counts = (int*)(ws + WS_CNT);
    float* pd = ws + WS_PD;
    int* pi = (int*)(ws + WS_PI);

    k_esq_zero<<<dim3(Kn / 256), dim3(256), 0, stream>>>(cb, e_sq, counts);
    k_naip<<<dim3(Bn), dim3(128), 0, stream>>>(naip, conv_w, conv_b, npw, npb, naip2);
    k_ze<<<dim3(BTn / 16), dim3(256), 0, stream>>>(cont, cat, emb_sp, emb_lc, cpw, cpb, caw, cab,
                                                   f1w, f1b, f2w, f2b, naip2, z_e);
    k_vq_partial<<<dim3(VQ_CHUNKS, BTn / VQ_TOK), dim3(256), 0, stream>>>(z_e, cb, e_sq, pd, pi);
    k_vq_reduce<<<dim3(BTn / 256), dim3(256), 0, stream>>>(pd, pi, z_e, cb, z_q, out + O_IDX,
                                                           counts, parts);
    k_backbone<<<dim3(BTn / 16), dim3(256), 0, stream>>>(z_q, bb1w, bb1b, bb2w, bb2b, chw, chb,
                                                         lcw, lcb, h, out + O_CONT, out + O_LC);
    k_sp<<<dim3(16, BTn / 128), dim3(256), 0, stream>>>(h, spw, spb, out + O_SP);
    k_canopy<<<dim3(Bn), dim3(128), 0, stream>>>(h, c1w, c1b, c2w, c2b, out + O_CAN);
    k_finalize<<<dim3(1), dim3(256), 0, stream>>>(parts, counts, out + O_LOSS, out + O_PPL);
}

// Round 4
// 500.826 us; speedup vs baseline: 3.0292x; 1.4804x over previous
//
#include <hip/hip_runtime.h>
#include <cmath>

namespace {
constexpr int Bn = 128, Tn = 128, BTn = Bn * Tn;
constexpr int CONTn = 16, HIDn = 128, EMBn = 64;
constexpr int Kn = 8192, CEn = 6, VSPn = 2000, VLCn = 32, FINn = 3 * HIDn;
constexpr int VQ_CHUNKS = 16;             // 512 codes per chunk
constexpr int VQ_TOK = 128;               // tokens per block
constexpr int VSP_PAD = 2048;             // padded vocab for MFMA tiles

// ---- workspace layout (float units) ----
constexpr size_t WS_NAIP2 = 0;                               // B*HID
constexpr size_t WS_ZE    = WS_NAIP2 + (size_t)Bn * HIDn;    // BT*EMB
constexpr size_t WS_ZQ    = WS_ZE + (size_t)BTn * EMBn;      // BT*EMB
constexpr size_t WS_H     = WS_ZQ + (size_t)BTn * EMBn;      // BT*HID
constexpr size_t WS_ESQ   = WS_H + (size_t)BTn * HIDn;       // K
constexpr size_t WS_PART  = WS_ESQ + Kn;                     // 64 partial loss sums
constexpr size_t WS_CNT   = WS_PART + 64;                    // K ints
constexpr size_t WS_PD    = WS_CNT + Kn;                     // VQ_CHUNKS*BT floats
constexpr size_t WS_PI    = WS_PD + (size_t)VQ_CHUNKS * BTn; // VQ_CHUNKS*BT ints
constexpr size_t WS_HBF   = WS_PI + (size_t)VQ_CHUNKS * BTn; // BT*HID ushorts = BT*64 floats
constexpr size_t WS_WBF   = WS_HBF + (size_t)BTn * 64;       // VSP_PAD*HID ushorts
constexpr size_t WS_END   = WS_WBF + (size_t)VSP_PAD * HIDn / 2;

// ---- output layout (float units) ----
constexpr size_t O_CONT = 0;
constexpr size_t O_SP   = O_CONT + (size_t)BTn * CONTn;
constexpr size_t O_LC   = O_SP + (size_t)BTn * VSPn;
constexpr size_t O_CAN  = O_LC + (size_t)BTn * VLCn;
constexpr size_t O_IDX  = O_CAN + Bn;
constexpr size_t O_LOSS = O_IDX + BTn;
constexpr size_t O_PPL  = O_LOSS + 1;
} // namespace

typedef __attribute__((ext_vector_type(8))) short short8v;  // 8 bf16 = 4 VGPR
typedef __attribute__((ext_vector_type(4))) float f32x4;

__device__ __forceinline__ float nan0(float v) {
    return __builtin_isfinite(v) ? v : 0.0f;
}
__device__ __forceinline__ float dot4(float4 a, float4 b) {
    return a.x * b.x + a.y * b.y + a.z * b.z + a.w * b.w;
}
__device__ __forceinline__ unsigned short f2bf(float f) { // RNE, finite-only
    union { float f; unsigned u; } v{f};
    unsigned r = v.u + 0x7FFFu + ((v.u >> 16) & 1u);
    return (unsigned short)(r >> 16);
}

// ---------------------------------------------------------------- K0: zero counts + codebook row norms
__global__ __launch_bounds__(256) void k_esq_zero(const float* __restrict__ cb,
                                                  float* __restrict__ e_sq,
                                                  int* __restrict__ counts) {
    int i = blockIdx.x * 256 + threadIdx.x;
    if (i < Kn) {
        counts[i] = 0;
        const float4* r = (const float4*)(cb + (size_t)i * EMBn);
        float s = 0.f;
#pragma unroll
        for (int j = 0; j < 16; ++j) { float4 v = r[j]; s += dot4(v, v); }
        e_sq[i] = s;
    }
}

// ---------------------------------------------------------------- K0b: sp_head_w -> bf16, padded to 2048 rows
__global__ __launch_bounds__(256) void k_wcast(const float* __restrict__ w,
                                               unsigned short* __restrict__ wbf) {
    int i = blockIdx.x * 256 + threadIdx.x;      // float4 index; 32 per row
    int v = i >> 5;
    unsigned short u[4] = {0, 0, 0, 0};
    if (v < VSPn) {
        float4 x = ((const float4*)w)[i];
        u[0] = f2bf(x.x); u[1] = f2bf(x.y); u[2] = f2bf(x.z); u[3] = f2bf(x.w);
    }
    *(uint2*)(wbf + (size_t)i * 4) = *(const uint2*)u;
}

// ---------------------------------------------------------------- K1: naip conv + proj -> naip2 (B x HID)
__global__ __launch_bounds__(128) void k_naip(const float* __restrict__ naip,
                                              const float* __restrict__ conv_w,
                                              const float* __restrict__ conv_b,
                                              const float* __restrict__ pw,
                                              const float* __restrict__ pb,
                                              float* __restrict__ naip2) {
    int b = blockIdx.x, o = threadIdx.x;
    __shared__ float feat[HIDn];
    float acc = conv_b[o];
#pragma unroll
    for (int i = 0; i < 9; ++i) acc += nan0(naip[b * 9 + i]) * conv_w[o * 9 + i];
    feat[o] = fmaxf(acc, 0.f);
    __syncthreads();
    float a2 = pb[o];
    const float4* wr = (const float4*)(pw + (size_t)o * HIDn);
    const float4* fr = (const float4*)feat;
#pragma unroll
    for (int j = 0; j < 32; ++j) a2 += dot4(fr[j], wr[j]);
    naip2[(size_t)b * HIDn + o] = a2;
}

// ---------------------------------------------------------------- K2: fused inputs -> z_e (BT x EMB)
__global__ __launch_bounds__(256) void k_ze(
    const float* __restrict__ cont, const int* __restrict__ cat,
    const float* __restrict__ emb_sp, const float* __restrict__ emb_lc,
    const float* __restrict__ cpw, const float* __restrict__ cpb,
    const float* __restrict__ caw, const float* __restrict__ cab,
    const float* __restrict__ f1w, const float* __restrict__ f1b,
    const float* __restrict__ f2w, const float* __restrict__ f2b,
    const float* __restrict__ naip2, float* __restrict__ z_e) {
    const int tok0 = blockIdx.x * 16;
    const int tid = threadIdx.x;
    __shared__ float fused[16][FINn + 4];
    __shared__ float h1[16][HIDn + 4];

    for (int idx = tid; idx < 16 * HIDn; idx += 256) {
        int t = idx >> 7, j = idx & 127;
        int b = (tok0 + t) / Tn;
        fused[t][j] = naip2[(size_t)b * HIDn + j];
    }
    for (int idx = tid; idx < 16 * HIDn; idx += 256) {
        int t = idx >> 7, o = idx & 127;
        int tok = tok0 + t;
        const float4* cp = (const float4*)(cont + (size_t)tok * CONTn);
        const float4* wr = (const float4*)(cpw + (size_t)o * CONTn);
        float a = cpb[o];
#pragma unroll
        for (int q = 0; q < 4; ++q) {
            float4 c4 = cp[q], w4 = wr[q];
            a += nan0(c4.x) * w4.x + nan0(c4.y) * w4.y + nan0(c4.z) * w4.z + nan0(c4.w) * w4.w;
        }
        fused[t][HIDn + o] = a;
    }
    for (int idx = tid; idx < 16 * HIDn; idx += 256) {
        int t = idx >> 7, o = idx & 127;
        int tok = tok0 + t;
        int c0 = cat[tok * 2], c1 = cat[tok * 2 + 1];
        const float* e0 = emb_sp + (size_t)c0 * CEn;
        const float* e1 = emb_lc + (size_t)c1 * CEn;
        const float* wr = caw + (size_t)o * (2 * CEn);
        float a = cab[o];
#pragma unroll
        for (int i = 0; i < CEn; ++i) a += e0[i] * wr[i];
#pragma unroll
        for (int i = 0; i < CEn; ++i) a += e1[i] * wr[CEn + i];
        fused[t][2 * HIDn + o] = a;
    }
    __syncthreads();
    {
        int o = tid >> 1, half = tid & 1;
        float acc[8];
        float bv = f1b[o];
#pragma unroll
        for (int t = 0; t < 8; ++t) acc[t] = bv;
        const float4* wr = (const float4*)(f1w + (size_t)o * FINn);
        for (int kk = 0; kk < FINn / 4; ++kk) {
            float4 w = wr[kk];
#pragma unroll
            for (int t = 0; t < 8; ++t) {
                float4 f = ((const float4*)&fused[half * 8 + t][0])[kk];
                acc[t] += dot4(f, w);
            }
        }
#pragma unroll
        for (int t = 0; t < 8; ++t) h1[half * 8 + t][o] = fmaxf(acc[t], 0.f);
    }
    __syncthreads();
    {
        int o = tid & 63, tg = tid >> 6;
        float acc[4];
        float bv = f2b[o];
#pragma unroll
        for (int t = 0; t < 4; ++t) acc[t] = bv;
        const float4* wr = (const float4*)(f2w + (size_t)o * HIDn);
        for (int kk = 0; kk < HIDn / 4; ++kk) {
            float4 w = wr[kk];
#pragma unroll
            for (int t = 0; t < 4; ++t) {
                float4 f = ((const float4*)&h1[tg * 4 + t][0])[kk];
                acc[t] += dot4(f, w);
            }
        }
#pragma unroll
        for (int t = 0; t < 4; ++t) z_e[(size_t)(tok0 + tg * 4 + t) * EMBn + o] = acc[t];
    }
}

// ---------------------------------------------------------------- K3a: VQ partial argmin over a 512-code chunk
struct alignas(16) VqShared {
    union {
        float ct[128][64];
        struct { float rd[128][17]; int ri[128][17]; } r;
    } u;
};

__global__ __launch_bounds__(256, 2) void k_vq_partial(
    const float* __restrict__ z_e, const float* __restrict__ cb,
    const float* __restrict__ e_sq, float* __restrict__ pd, int* __restrict__ pi) {
    const int tid = threadIdx.x;
    const int x = tid & 15;
    const int y = tid >> 4;
    const int chunk = blockIdx.x;
    const int c_base = chunk * (Kn / VQ_CHUNKS);
    const int tok0 = blockIdx.y * VQ_TOK;

    __shared__ float zt[VQ_TOK][64];
    __shared__ VqShared s;
    __shared__ float es[128];

    for (int idx = tid; idx < VQ_TOK * 16; idx += 256) {
        int t = idx >> 4, q = idx & 15;
        ((float4*)&zt[t][0])[q ^ (t >> 3)] =
            ((const float4*)(z_e + (size_t)(tok0 + t) * EMBn))[q];
    }

    float bd[8];
    int bi[8];
#pragma unroll
    for (int t = 0; t < 8; ++t) { bd[t] = INFINITY; bi[t] = 0; }

    for (int tile = 0; tile < (Kn / VQ_CHUNKS) / 128; ++tile) {
        const int c0 = c_base + tile * 128;
        __syncthreads();
        for (int idx = tid; idx < 128 * 16; idx += 256) {
            int c = idx >> 4, q = idx & 15;
            ((float4*)&s.u.ct[c][0])[q ^ (c & 15)] =
                ((const float4*)(cb + (size_t)(c0 + c) * EMBn))[q];
        }
        if (tid < 128) es[tid] = e_sq[c0 + tid];
        __syncthreads();

        float acc[8][8];
#pragma unroll
        for (int t = 0; t < 8; ++t)
#pragma unroll
            for (int j = 0; j < 8; ++j) acc[t][j] = 0.f;

#pragma unroll 4
        for (int kk = 0; kk < 16; ++kk) {
            float4 zz[8];
#pragma unroll
            for (int t = 0; t < 8; ++t)
                zz[t] = ((const float4*)&zt[y * 8 + t][0])[kk ^ y];
#pragma unroll
            for (int j = 0; j < 8; ++j) {
                float4 c4 = ((const float4*)&s.u.ct[x + 16 * j][0])[kk ^ x];
#pragma unroll
                for (int t = 0; t < 8; ++t) acc[t][j] += dot4(zz[t], c4);
            }
        }
#pragma unroll
        for (int j = 0; j < 8; ++j) {
            int c = c0 + x + 16 * j;
            float e = es[x + 16 * j];
#pragma unroll
            for (int t = 0; t < 8; ++t) {
                float d = e - 2.f * acc[t][j];
                if (d < bd[t]) { bd[t] = d; bi[t] = c; }
            }
        }
    }
    __syncthreads();
#pragma unroll
    for (int t = 0; t < 8; ++t) { s.u.r.rd[y * 8 + t][x] = bd[t]; s.u.r.ri[y * 8 + t][x] = bi[t]; }
    __syncthreads();
    if (tid < VQ_TOK) {
        float best = s.u.r.rd[tid][0];
        int b_ = s.u.r.ri[tid][0];
#pragma unroll
        for (int xx = 1; xx < 16; ++xx) {
            float d = s.u.r.rd[tid][xx];
            int i2 = s.u.r.ri[tid][xx];
            if (d < best || (d == best && i2 < b_)) { best = d; b_ = i2; }
        }
        pd[(size_t)chunk * BTn + tok0 + tid] = best;
        pi[(size_t)chunk * BTn + tok0 + tid] = b_;
    }
}

// ---------------------------------------------------------------- K3b: merge chunks, gather z_q, counts, loss
__global__ __launch_bounds__(256) void k_vq_reduce(
    const float* __restrict__ pd, const int* __restrict__ pi,
    const float* __restrict__ z_e, const float* __restrict__ cb,
    float* __restrict__ z_q, float* __restrict__ idx_out,
    int* __restrict__ counts, float* __restrict__ partials) {
    const int tid = threadIdx.x;
    const int tok = blockIdx.x * 256 + tid;
    float best = pd[tok];
    int b_ = pi[tok];
#pragma unroll
    for (int c = 1; c < VQ_CHUNKS; ++c) {
        float d = pd[(size_t)c * BTn + tok];
        int i2 = pi[(size_t)c * BTn + tok];
        if (d < best || (d == best && i2 < b_)) { best = d; b_ = i2; }
    }
    idx_out[tok] = (float)b_;
    atomicAdd(&counts[b_], 1);

    float lsum = 0.f;
    const float4* cr = (const float4*)(cb + (size_t)b_ * EMBn);
    const float4* zr = (const float4*)(z_e + (size_t)tok * EMBn);
    float4* qr = (float4*)(z_q + (size_t)tok * EMBn);
#pragma unroll
    for (int q = 0; q < 16; ++q) {
        float4 cq = cr[q];
        qr[q] = cq;
        float4 zz = zr[q];
        float dx = zz.x - cq.x, dy = zz.y - cq.y, dz = zz.z - cq.z, dw = zz.w - cq.w;
        lsum += dx * dx + dy * dy + dz * dz + dw * dw;
    }
    __shared__ float red[256];
    red[tid] = lsum;
    __syncthreads();
    for (int sdist = 128; sdist > 0; sdist >>= 1) {
        if (tid < sdist) red[tid] += red[tid + sdist];
        __syncthreads();
    }
    if (tid == 0) partials[blockIdx.x] = red[0];
}

// ---------------------------------------------------------------- K4: backbone + small heads (+ h in bf16)
__global__ __launch_bounds__(256) void k_backbone(
    const float* __restrict__ z_q,
    const float* __restrict__ bb1w, const float* __restrict__ bb1b,
    const float* __restrict__ bb2w, const float* __restrict__ bb2b,
    const float* __restrict__ chw, const float* __restrict__ chb,
    const float* __restrict__ lcw, const float* __restrict__ lcb,
    float* __restrict__ h_out, unsigned short* __restrict__ hbf_out,
    float* __restrict__ cont_rec, float* __restrict__ lc_out) {
    const int tid = threadIdx.x;
    const int tok0 = blockIdx.x * 16;
    __shared__ float zq[16][68];
    __shared__ float h1[16][HIDn + 4];
    __shared__ float h2[16][HIDn + 4];
    {
        int t = tid >> 4, q = tid & 15;
        ((float4*)&zq[t][0])[q] = ((const float4*)(z_q + (size_t)(tok0 + t) * EMBn))[q];
    }
    __syncthreads();
    {
        int o = tid >> 1, half = tid & 1;
        float acc[8];
        float bv = bb1b[o];
#pragma unroll
        for (int t = 0; t < 8; ++t) acc[t] = bv;
        const float4* wr = (const float4*)(bb1w + (size_t)o * EMBn);
#pragma unroll
        for (int kk = 0; kk < 16; ++kk) {
            float4 w = wr[kk];
#pragma unroll
            for (int t = 0; t < 8; ++t) acc[t] += dot4(((const float4*)&zq[half * 8 + t][0])[kk], w);
        }
#pragma unroll
        for (int t = 0; t < 8; ++t) h1[half * 8 + t][o] = fmaxf(acc[t], 0.f);
    }
    __syncthreads();
    {
        int o = tid >> 1, half = tid & 1;
        float acc[8];
        float bv = bb2b[o];
#pragma unroll
        for (int t = 0; t < 8; ++t) acc[t] = bv;
        const float4* wr = (const float4*)(bb2w + (size_t)o * HIDn);
        for (int kk = 0; kk < 32; ++kk) {
            float4 w = wr[kk];
#pragma unroll
            for (int t = 0; t < 8; ++t) acc[t] += dot4(((const float4*)&h1[half * 8 + t][0])[kk], w);
        }
#pragma unroll
        for (int t = 0; t < 8; ++t) {
            float v = fmaxf(acc[t], 0.f);
            h2[half * 8 + t][o] = v;
            h_out[(size_t)(tok0 + half * 8 + t) * HIDn + o] = v;
            hbf_out[(size_t)(tok0 + half * 8 + t) * HIDn + o] = f2bf(v);
        }
    }
    __syncthreads();
    {
        int t = tid >> 4, o = tid & 15;
        float a = chb[o];
        const float4* wr = (const float4*)(chw + (size_t)o * HIDn);
#pragma unroll
        for (int kk = 0; kk < 32; ++kk) a += dot4(((const float4*)&h2[t][0])[kk], wr[kk]);
        cont_rec[(size_t)(tok0 + t) * CONTn + o] = a;
    }
    for (int idx = tid; idx < 16 * 32; idx += 256) {
        int t = idx >> 5, o = idx & 31;
        float a = lcb[o];
        const float4* wr = (const float4*)(lcw + (size_t)o * HIDn);
#pragma unroll
        for (int kk = 0; kk < 32; ++kk) a += dot4(((const float4*)&h2[t][0])[kk], wr[kk]);
        lc_out[(size_t)(tok0 + t) * VLCn + o] = a;
    }
}

// ---------------------------------------------------------------- K5: sp_logits via bf16 MFMA, direct-from-L2 frags
// grid (16, 128); block 256 = 4 waves; block tile 128 tok x 128 vocab; wave tile 64x64.
__global__ __launch_bounds__(256, 3) void k_sp_mfma(
    const unsigned short* __restrict__ hbf, const unsigned short* __restrict__ wbf,
    const float* __restrict__ bias, float* __restrict__ out) {
    const int tid = threadIdx.x;
    const int lane = tid & 63;
    const int wid = tid >> 6;
    const int tok_w = blockIdx.y * 128 + (wid & 1) * 64;
    const int v_w = blockIdx.x * 128 + (wid >> 1) * 64;

    const int lrow = lane & 15;
    const int lk = (lane >> 4) * 8;

    const unsigned short* ha = hbf + (size_t)(tok_w + lrow) * HIDn + lk;
    const unsigned short* wa = wbf + (size_t)(v_w + lrow) * HIDn + lk;

    f32x4 acc[4][4];
#pragma unroll
    for (int m = 0; m < 4; ++m)
#pragma unroll
        for (int n = 0; n < 4; ++n) acc[m][n] = (f32x4){0.f, 0.f, 0.f, 0.f};

#pragma unroll
    for (int ks = 0; ks < 4; ++ks) {
        const int kk = ks * 32;
        short8v a[4], b[4];
#pragma unroll
        for (int m = 0; m < 4; ++m)
            a[m] = *(const short8v*)(ha + (size_t)m * 16 * HIDn + kk);
#pragma unroll
        for (int n = 0; n < 4; ++n)
            b[n] = *(const short8v*)(wa + (size_t)n * 16 * HIDn + kk);
#pragma unroll
        for (int m = 0; m < 4; ++m)
#pragma unroll
            for (int n = 0; n < 4; ++n)
                acc[m][n] = __builtin_amdgcn_mfma_f32_16x16x32_bf16(a[m], b[n], acc[m][n], 0, 0, 0);
    }

    // epilogue: C[row = (lane>>4)*4 + r][col = lane&15] per 16x16 frag
    const int r0 = (lane >> 4) * 4;
#pragma unroll
    for (int n = 0; n < 4; ++n) {
        const int col = v_w + n * 16 + lrow;
        if (col < VSPn) {
            const float bv = bias[col];
#pragma unroll
            for (int m = 0; m < 4; ++m) {
                const int row = tok_w + m * 16 + r0;
#pragma unroll
                for (int r = 0; r < 4; ++r)
                    out[(size_t)(row + r) * VSPn + col] = acc[m][n][r] + bv;
            }
        }
    }
}

// ---------------------------------------------------------------- K6: canopy head on h[:, -1, :]
__global__ __launch_bounds__(128) void k_canopy(const float* __restrict__ h,
                                                const float* __restrict__ w1,
                                                const float* __restrict__ b1,
                                                const float* __restrict__ w2,
                                                const float* __restrict__ b2,
                                                float* __restrict__ can) {
    int b = blockIdx.x, o = threadIdx.x;
    __shared__ float r[128];
    const float4* hr = (const float4*)(h + (size_t)(b * Tn + Tn - 1) * HIDn);
    const float4* wr = (const float4*)(w1 + (size_t)o * HIDn);
    float a = b1[o];
#pragma unroll
    for (int kk = 0; kk < 32; ++kk) a += dot4(hr[kk], wr[kk]);
    r[o] = fmaxf(a, 0.f) * w2[o];
    __syncthreads();
    for (int s = 64; s > 0; s >>= 1) {
        if (o < s) r[o] += r[o + s];
        __syncthreads();
    }
    if (o == 0) can[b] = r[0] + b2[0];
}

// ---------------------------------------------------------------- K7: loss + perplexity
__global__ __launch_bounds__(256) void k_finalize(const float* __restrict__ partials,
                                                  const int* __restrict__ counts,
                                                  float* __restrict__ out_loss,
                                                  float* __restrict__ out_ppl) {
    const int tid = threadIdx.x;
    __shared__ float red[256];
    red[tid] = (tid < 64) ? partials[tid] : 0.f;
    __syncthreads();
    for (int s = 128; s > 0; s >>= 1) {
        if (tid < s) red[tid] += red[tid + s];
        __syncthreads();
    }
    float total = red[0];
    __syncthreads();
    float e = 0.f;
    for (int i = tid; i < Kn; i += 256) {
        float p = (float)counts[i] * (1.0f / BTn);
        e += p * logf(p + 1e-12f);
    }
    red[tid] = e;
    __syncthreads();
    for (int s = 128; s > 0; s >>= 1) {
        if (tid < s) red[tid] += red[tid + s];
        __syncthreads();
    }
    if (tid == 0) {
        out_loss[0] = 1.25f * total / (float)((size_t)BTn * EMBn);
        out_ppl[0] = expf(-red[0]);
    }
}

// ----------------------------------------------------------------
extern "C" void kernel_launch(void* const* d_in, const int* in_sizes, int n_in,
                              void* d_out, int out_size, void* d_ws, size_t ws_size,
                              hipStream_t stream) {
    const float* cont = (const float*)d_in[0];
    const float* naip = (const float*)d_in[1];
    const int* cat = (const int*)d_in[2];
    const float* emb_sp = (const float*)d_in[3];
    const float* emb_lc = (const float*)d_in[4];
    const float* conv_w = (const float*)d_in[5];
    const float* conv_b = (const float*)d_in[6];
    const float* npw = (const float*)d_in[7];
    const float* npb = (const float*)d_in[8];
    const float* cpw = (const float*)d_in[9];
    const float* cpb = (const float*)d_in[10];
    const float* caw = (const float*)d_in[11];
    const float* cab = (const float*)d_in[12];
    const float* f1w = (const float*)d_in[13];
    const float* f1b = (const float*)d_in[14];
    const float* f2w = (const float*)d_in[15];
    const float* f2b = (const float*)d_in[16];
    const float* cb = (const float*)d_in[17];
    const float* bb1w = (const float*)d_in[18];
    const float* bb1b = (const float*)d_in[19];
    const float* bb2w = (const float*)d_in[20];
    const float* bb2b = (const float*)d_in[21];
    const float* chw = (const float*)d_in[22];
    const float* chb = (const float*)d_in[23];
    const float* spw = (const float*)d_in[24];
    const float* spb = (const float*)d_in[25];
    const float* lcw = (const float*)d_in[26];
    const float* lcb = (const float*)d_in[27];
    const float* c1w = (const float*)d_in[28];
    const float* c1b = (const float*)d_in[29];
    const float* c2w = (const float*)d_in[30];
    const float* c2b = (const float*)d_in[31];

    float* out = (float*)d_out;
    float* ws = (float*)d_ws;
    float* naip2 = ws + WS_NAIP2;
    float* z_e = ws + WS_ZE;
    float* z_q = ws + WS_ZQ;
    float* h = ws + WS_H;
    float* e_sq = ws + WS_ESQ;
    float* parts = ws + WS_PART;
    int* counts = (int*)(ws + WS_CNT);
    float* pd = ws + WS_PD;
    int* pi = (int*)(ws + WS_PI);
    unsigned short* hbf = (unsigned short*)(ws + WS_HBF);
    unsigned short* wbf = (unsigned short*)(ws + WS_WBF);

    k_esq_zero<<<dim3(Kn / 256), dim3(256), 0, stream>>>(cb, e_sq, counts);
    k_wcast<<<dim3(VSP_PAD * HIDn / 4 / 256), dim3(256), 0, stream>>>(spw, wbf);
    k_naip<<<dim3(Bn), dim3(128), 0, stream>>>(naip, conv_w, conv_b, npw, npb, naip2);
    k_ze<<<dim3(BTn / 16), dim3(256), 0, stream>>>(cont, cat, emb_sp, emb_lc, cpw, cpb, caw, cab,
                                                   f1w, f1b, f2w, f2b, naip2, z_e);
    k_vq_partial<<<dim3(VQ_CHUNKS, BTn / VQ_TOK), dim3(256), 0, stream>>>(z_e, cb, e_sq, pd, pi);
    k_vq_reduce<<<dim3(BTn / 256), dim3(256), 0, stream>>>(pd, pi, z_e, cb, z_q, out + O_IDX,
                                                           counts, parts);
    k_backbone<<<dim3(BTn / 16), dim3(256), 0, stream>>>(z_q, bb1w, bb1b, bb2w, bb2b, chw, chb,
                                                         lcw, lcb, h, hbf, out + O_CONT, out + O_LC);
    k_sp_mfma<<<dim3(VSP_PAD / 128, BTn / 128), dim3(256), 0, stream>>>(hbf, wbf, spb, out + O_SP);
    k_canopy<<<dim3(Bn), dim3(128), 0, stream>>>(h, c1w, c1b, c2w, c2b, out + O_CAN);
    k_finalize<<<dim3(1), dim3(256), 0, stream>>>(parts, counts, out + O_LOSS, out + O_PPL);
}